// Round 14
// baseline (5304.271 us; speedup 1.0000x reference)
//
#include <hip/hip_runtime.h>
#include <hip/hip_bf16.h>

#define LEAKY(v) ((v) >= 0.0f ? (v) : 0.01f * (v))

typedef int iv4 __attribute__((ext_vector_type(4)));
typedef unsigned short us4 __attribute__((ext_vector_type(4)));
typedef short s8v __attribute__((ext_vector_type(8)));     // 8 bf16 (4 VGPRs)
typedef float f4 __attribute__((ext_vector_type(4)));      // MFMA acc

constexpr int SH = 8;        // rows per bucket = 256
constexpr int RPB = 1 << SH; // 256
constexpr int NBMAX = 640;   // max buckets (n <= 163840)
constexpr int CHUNK = 6144;  // edges per phase-1 block

__device__ __forceinline__ unsigned short f2bf(float v) {
  unsigned u = __float_as_uint(v);
  return (unsigned short)((u + 0x7fffu + ((u >> 16) & 1u)) >> 16);  // RNE
}
__device__ __forceinline__ float bf2f(unsigned short h) {
  return __uint_as_float((unsigned)h << 16);
}

// ---------------------------------------------------------------------------
// k_init: ego -> out cols [0,64) (f32) and bf16 gather table xh.
// ---------------------------------------------------------------------------
__global__ void k_init(const float* __restrict__ ego, float* __restrict__ out,
                       unsigned short* __restrict__ xh, int n) {
  int tid = blockIdx.x * blockDim.x + threadIdx.x;
  int total = n * 16;
  int stride = gridDim.x * blockDim.x;
  for (int t = tid; t < total; t += stride) {
    int r = t >> 4, c = (t & 15) * 4;
    float4 v = *(const float4*)(ego + (size_t)r * 64 + c);
    *(float4*)(out + (size_t)r * 176 + c) = v;
    us4 h;
    h.x = f2bf(v.x); h.y = f2bf(v.y); h.z = f2bf(v.z); h.w = f2bf(v.w);
    *(us4*)(xh + (size_t)r * 64 + c) = h;
  }
}

// ---------------------------------------------------------------------------
// k_hist: bucket (row>>SH) histogram, LDS-staged.
// ---------------------------------------------------------------------------
__global__ void __launch_bounds__(256) k_hist(const int* __restrict__ erow,
                                              int* __restrict__ bcnt, int E, int nb) {
  __shared__ int h[NBMAX];
  for (int i = threadIdx.x; i < NBMAX; i += 256) h[i] = 0;
  __syncthreads();
  int tid = blockIdx.x * blockDim.x + threadIdx.x;
  int stride = gridDim.x * blockDim.x;
  for (int e = tid; e < E; e += stride) atomicAdd(&h[erow[e] >> SH], 1);
  __syncthreads();
  for (int b = threadIdx.x; b < nb; b += 256)
    if (h[b]) atomicAdd(&bcnt[b], h[b]);
}

// ---------------------------------------------------------------------------
// k_scanb: one wave: boff = exclusive scan of bcnt; bcur = boff.
// ---------------------------------------------------------------------------
__global__ void k_scanb(const int* __restrict__ bcnt, int* __restrict__ boff,
                        int* __restrict__ bcur, int nb) {
  int l = threadIdx.x;  // 64 threads
  constexpr int PB = NBMAX / 64;  // 10
  int local[PB];
  int s = 0;
  int base = l * PB;
  for (int j = 0; j < PB; ++j) {
    int b = base + j;
    int c = (b < nb) ? bcnt[b] : 0;
    local[j] = c;
    s += c;
  }
  int incl = s;
  for (int d = 1; d < 64; d <<= 1) {
    int v = __shfl_up(incl, d);
    if (l >= d) incl += v;
  }
  int ex = incl - s;
  for (int j = 0; j < PB; ++j) {
    int b = base + j;
    if (b <= nb) { boff[b] = ex; bcur[b] = ex; }
    ex += local[j];
  }
  if (l == 63) boff[nb] = incl;
}

// ---------------------------------------------------------------------------
// k_bucket: LDS counting-sort of a 6144-edge chunk by bucket; reserve
// per-bucket global slices; write bucket-contiguous runs.
// Entry: (localrow<<18 | col, valbits) — col < 2^18, localrow < 256.
// ---------------------------------------------------------------------------
__global__ void __launch_bounds__(256) k_bucket(
    const int* __restrict__ erow, const int* __restrict__ ecol,
    const float* __restrict__ ev, int* __restrict__ bcur,
    int2* __restrict__ bkt, int E, int nb) {
  __shared__ int hist[NBMAX];
  __shared__ int excl[NBMAX + 1];
  __shared__ int curl[NBMAX];
  __shared__ int gbase[NBMAX];
  __shared__ int2 skv[CHUNK];
  int base = blockIdx.x * CHUNK;
  int cnt = min(CHUNK, E - base);

  for (int i = threadIdx.x; i < NBMAX; i += 256) hist[i] = 0;
  __syncthreads();
  for (int i = threadIdx.x; i < cnt; i += 256)
    atomicAdd(&hist[erow[base + i] >> SH], 1);
  __syncthreads();

  if (threadIdx.x < 64) {
    int l = threadIdx.x;
    constexpr int PB = NBMAX / 64;
    int lsum[PB];
    int s = 0;
    for (int j = 0; j < PB; ++j) { lsum[j] = hist[l * PB + j]; s += lsum[j]; }
    int incl = s;
    for (int d = 1; d < 64; d <<= 1) {
      int v = __shfl_up(incl, d);
      if (l >= d) incl += v;
    }
    int ex = incl - s;
    for (int j = 0; j < PB; ++j) { excl[l * PB + j] = ex; ex += lsum[j]; }
    if (l == 63) excl[NBMAX] = incl;
  }
  __syncthreads();

  for (int b = threadIdx.x; b < nb; b += 256) {
    curl[b] = 0;
    int c = hist[b];
    if (c) gbase[b] = atomicAdd(&bcur[b], c);
  }
  __syncthreads();

  for (int i = threadIdx.x; i < cnt; i += 256) {
    int r = erow[base + i];
    int b = r >> SH;
    int lr = r & (RPB - 1);
    int slot = excl[b] + atomicAdd(&curl[b], 1);
    int2 p;
    p.x = (lr << 18) | ecol[base + i];
    p.y = __float_as_int(ev[base + i]);
    skv[slot] = p;
  }
  __syncthreads();

  for (int s = threadIdx.x; s < cnt; s += 256) {
    int lo = 0, hi = nb;
    while (hi - lo > 1) {
      int mid = (lo + hi) >> 1;
      if (excl[mid] <= s) lo = mid; else hi = mid;
    }
    bkt[gbase[lo] + (s - excl[lo])] = skv[s];
  }
}

// ---------------------------------------------------------------------------
// k_gam: bucket-granular gather-SpMM. One 256-row bucket per block (512 thr,
// 8 waves). side accumulated in LDS f32 [256][DIN+1] (pad -> ~2-way banks)
// via LDS atomics. Each edge handled by LPE=DIN/8 lanes gathering 16B chunks
// of xh[col] (1 address per 16B). Epilogue: a = x+side, m = x*side ->
// amp[row][f] = bf16(a) | bf16(m)<<16.
// ---------------------------------------------------------------------------
template <int DIN>
__global__ void __launch_bounds__(512) k_gam(
    const int* __restrict__ boff, const int2* __restrict__ bkt,
    const unsigned short* __restrict__ xh, const float* __restrict__ xin,
    unsigned* __restrict__ amp, int n) {
  constexpr int LPE = DIN / 8;   // lanes per edge (8 or 4)
  constexpr int EPW = 64 / LPE;  // edges per wave-iter (8 or 16)
  __shared__ float side[RPB][DIN + 1];

  int tid = threadIdx.x;
  int w = tid >> 6, lane = tid & 63;
  int g = lane / LPE, c = lane % LPE;
  int b = blockIdx.x;

  for (int i = tid; i < RPB * (DIN + 1); i += 512) ((float*)side)[i] = 0.0f;
  __syncthreads();

  int off = boff[b], end = boff[b + 1];
  for (int base = off + w * EPW; base < end; base += 8 * EPW) {
    int idx = base + g;
    int2 q = bkt[min(idx, end - 1)];
    float val = (idx < end) ? __int_as_float(q.y) : 0.0f;
    int lr = q.x >> 18;
    int col = q.x & 0x3FFFF;
    s8v xr = *(const s8v*)(xh + (size_t)(unsigned)col * 64 + c * 8);
    float* srow = &side[lr][c * 8];
#pragma unroll
    for (int j = 0; j < 4; ++j) {
      unsigned d = ((const unsigned*)&xr)[j];
      atomicAdd(&srow[2 * j], val * __uint_as_float(d << 16));
      atomicAdd(&srow[2 * j + 1], val * __uint_as_float(d & 0xffff0000u));
    }
  }
  __syncthreads();

  int row0 = b << SH;
  if constexpr (DIN == 64) {
    for (int r = w; r < RPB; r += 8) {
      int grow = row0 + r;
      if (grow < n) {
        float s = side[r][lane];
        float xv = xin[(size_t)grow * 176 + lane];
        float a = xv + s, m = xv * s;
        amp[(size_t)grow * 64 + lane] = (unsigned)f2bf(a) | ((unsigned)f2bf(m) << 16);
      }
    }
  } else {
    int half = lane >> 5, f = lane & 31;
    for (int r = w * 2 + half; r < RPB; r += 16) {
      int grow = row0 + r;
      if (grow < n) {
        float s = side[r][f];
        float xv = xin[(size_t)grow * 176 + f];
        float a = xv + s, m = xv * s;
        amp[(size_t)grow * 64 + f] = (unsigned)f2bf(a) | ((unsigned)f2bf(m) << 16);
      }
    }
  }
}

// ---------------------------------------------------------------------------
// k_xf: MFMA transform. Block = 64 rows, 4 waves; wave w owns rows w*16..+16.
//   xn = leaky(A@W1 + b1) + leaky(M@W2 + b2)
// A/M and transposed W1/W2 staged in XOR-swizzled LDS.
// Writes f32 out (+ bf16 gather table xh for the next layer, if non-null).
// ---------------------------------------------------------------------------
template <int DIN, int DOUT>
__global__ void __launch_bounds__(256) k_xf(
    const unsigned* __restrict__ amp,
    const float* __restrict__ W1, const float* __restrict__ b1,
    const float* __restrict__ W2, const float* __restrict__ b2,
    float* __restrict__ outp, unsigned short* __restrict__ xh, int n) {
  constexpr int ROWB = DIN * 2;          // LDS row stride (bytes)
  constexpr int RMASK = (ROWB / 16) - 1; // swizzle mask
  constexpr int NTC = DOUT / 16;
  __shared__ unsigned short sA[64 * DIN];
  __shared__ unsigned short sM[64 * DIN];
  __shared__ unsigned short sW1[DOUT * DIN];
  __shared__ unsigned short sW2[DOUT * DIN];

  int row0 = blockIdx.x * 64;

  constexpr int PAIRS = DIN / 2;
  for (int i = threadIdx.x; i < 64 * PAIRS; i += 256) {
    int r = i / PAIRS, fp = (i - r * PAIRS) * 2;
    unsigned lo = 0, hi = 0;
    if (row0 + r < n) {
      uint2 q = *(const uint2*)(amp + (size_t)(row0 + r) * 64 + fp);
      lo = (q.x & 0xffffu) | ((q.y & 0xffffu) << 16);  // a pair
      hi = (q.x >> 16) | (q.y & 0xffff0000u);          // m pair
    }
    int boffb = r * ROWB + ((fp * 2) ^ ((r & RMASK) << 4));
    *(unsigned*)((char*)sA + boffb) = lo;
    *(unsigned*)((char*)sM + boffb) = hi;
  }
  for (int i = threadIdx.x; i < DIN * DOUT; i += 256) {
    int k = i / DOUT, c = i - k * DOUT;
    int boffb = c * ROWB + ((k * 2) ^ ((c & RMASK) << 4));
    *(unsigned short*)((char*)sW1 + boffb) = f2bf(W1[i]);
    *(unsigned short*)((char*)sW2 + boffb) = f2bf(W2[i]);
  }
  __syncthreads();

  int w = threadIdx.x >> 6, l = threadIdx.x & 63;
  int tr = w;

  f4 acc1[NTC], acc2[NTC];
#pragma unroll
  for (int tc = 0; tc < NTC; ++tc) {
    acc1[tc] = (f4){0.0f, 0.0f, 0.0f, 0.0f};
    acc2[tc] = (f4){0.0f, 0.0f, 0.0f, 0.0f};
  }

#pragma unroll
  for (int k0 = 0; k0 < DIN; k0 += 32) {
    int ra = tr * 16 + (l & 15);
    int inb = (k0 + (l >> 4) * 8) * 2;
    s8v af = *(const s8v*)((const char*)sA + ra * ROWB + (inb ^ ((ra & RMASK) << 4)));
    s8v mf = *(const s8v*)((const char*)sM + ra * ROWB + (inb ^ ((ra & RMASK) << 4)));
#pragma unroll
    for (int tc = 0; tc < NTC; ++tc) {
      int rc = tc * 16 + (l & 15);
      int wb = rc * ROWB + (inb ^ ((rc & RMASK) << 4));
      s8v w1 = *(const s8v*)((const char*)sW1 + wb);
      s8v w2 = *(const s8v*)((const char*)sW2 + wb);
      acc1[tc] = __builtin_amdgcn_mfma_f32_16x16x32_bf16(af, w1, acc1[tc], 0, 0, 0);
      acc2[tc] = __builtin_amdgcn_mfma_f32_16x16x32_bf16(mf, w2, acc2[tc], 0, 0, 0);
    }
  }

#pragma unroll
  for (int tc = 0; tc < NTC; ++tc) {
    int c = tc * 16 + (l & 15);
    float bb1 = b1[c], bb2 = b2[c];
#pragma unroll
    for (int j = 0; j < 4; ++j) {
      int r = tr * 16 + (l >> 4) * 4 + j;
      if (row0 + r < n) {
        float v1 = acc1[tc][j] + bb1;
        float v2 = acc2[tc][j] + bb2;
        float xn = LEAKY(v1) + LEAKY(v2);
        outp[(size_t)(row0 + r) * 176 + c] = xn;
        if (xh) xh[(size_t)(row0 + r) * 64 + c] = f2bf(xn);
      }
    }
  }
}

// ---------------------------------------------------------------------------
// k_norm: L2-normalize cols [64,128), [128,160), [160,176) in place.
// ---------------------------------------------------------------------------
__global__ void __launch_bounds__(256) k_norm(float* out, int n) {
  int row = (int)((blockIdx.x * (unsigned)blockDim.x + threadIdx.x) >> 6);
  int lane = threadIdx.x & 63;
  if (row >= n) return;
  float* r = out + (size_t)row * 176;
  float a = r[64 + lane];
  float b = (lane < 48) ? r[128 + lane] : 0.0f;
  float sa = a * a;
  float sb_ = (lane < 32) ? b * b : 0.0f;
  float sc = (lane >= 32 && lane < 48) ? b * b : 0.0f;
#pragma unroll
  for (int off = 32; off; off >>= 1) {
    sa += __shfl_xor(sa, off);
    sb_ += __shfl_xor(sb_, off);
    sc += __shfl_xor(sc, off);
  }
  float ia = 1.0f / fmaxf(sqrtf(sa), 1e-12f);
  float ib = 1.0f / fmaxf(sqrtf(sb_), 1e-12f);
  float ic = 1.0f / fmaxf(sqrtf(sc), 1e-12f);
  r[64 + lane] = a * ia;
  if (lane < 48) r[128 + lane] = b * ((lane < 32) ? ib : ic);
}

// ---------------------------------------------------------------------------
extern "C" void kernel_launch(void* const* d_in, const int* in_sizes, int n_in,
                              void* d_out, int out_size, void* d_ws, size_t ws_size,
                              hipStream_t stream) {
  const float* ego = (const float*)d_in[0];
  const int* erow = (const int*)d_in[1];
  const int* ecol = (const int*)d_in[2];
  const float* ev = (const float*)d_in[3];
  const int n = in_sizes[0] / 64;  // 160000
  const int E = in_sizes[1];       // 5120000
  const int nb = (n + RPB - 1) >> SH;  // 625

  float* out = (float*)d_out;  // [n, 176] f32

  // ws: bkt[E] 41MB | amp[n*64] u32 41MB | bcnt|boff|bcur | xh[n*64] bf16 20.5MB
  // total ~102.4 MB (proven budget >= 103.1 MB from rounds 11-13 bf path)
  int2* bkt = (int2*)d_ws;
  unsigned* amp = (unsigned*)(bkt + E);
  int* bcnt = (int*)(amp + (size_t)n * 64);
  int* boff = bcnt + NBMAX;
  int* bcur = boff + NBMAX + 1;
  unsigned short* xh = (unsigned short*)(bcur + NBMAX);

  const int rblocks = (n + 3) / 4;   // k_norm: one wave per row
  const int xblocks = (n + 63) / 64; // k_xf: 64 rows per block

  k_init<<<2048, 256, 0, stream>>>(ego, out, xh, n);
  hipMemsetAsync(bcnt, 0, NBMAX * sizeof(int), stream);
  k_hist<<<1024, 256, 0, stream>>>(erow, bcnt, E, nb);
  k_scanb<<<1, 64, 0, stream>>>(bcnt, boff, bcur, nb);
  k_bucket<<<(E + CHUNK - 1) / CHUNK, 256, 0, stream>>>(erow, ecol, ev, bcur, bkt, E, nb);

  const float* W1_0 = (const float*)d_in[4];
  const float* B1_0 = (const float*)d_in[5];
  const float* W2_0 = (const float*)d_in[6];
  const float* B2_0 = (const float*)d_in[7];
  const float* W1_1 = (const float*)d_in[8];
  const float* B1_1 = (const float*)d_in[9];
  const float* W2_1 = (const float*)d_in[10];
  const float* B2_1 = (const float*)d_in[11];
  const float* W1_2 = (const float*)d_in[12];
  const float* B1_2 = (const float*)d_in[13];
  const float* W2_2 = (const float*)d_in[14];
  const float* B2_2 = (const float*)d_in[15];

  k_gam<64><<<nb, 512, 0, stream>>>(boff, bkt, xh, out, amp, n);
  k_xf<64, 64><<<xblocks, 256, 0, stream>>>(amp, W1_0, B1_0, W2_0, B2_0, out + 64, xh, n);
  k_gam<64><<<nb, 512, 0, stream>>>(boff, bkt, xh, out + 64, amp, n);
  k_xf<64, 32><<<xblocks, 256, 0, stream>>>(amp, W1_1, B1_1, W2_1, B2_1, out + 128, xh, n);
  k_gam<32><<<nb, 512, 0, stream>>>(boff, bkt, xh, out + 128, amp, n);
  k_xf<32, 16><<<xblocks, 256, 0, stream>>>(amp, W1_2, B1_2, W2_2, B2_2, out + 160, nullptr, n);

  k_norm<<<rblocks, 256, 0, stream>>>(out, n);
}

// Round 16
// 790.826 us; speedup vs baseline: 6.7073x; 6.7073x over previous
//
#include <hip/hip_runtime.h>
#include <hip/hip_bf16.h>

#define LEAKY(v) ((v) >= 0.0f ? (v) : 0.01f * (v))

typedef int iv4 __attribute__((ext_vector_type(4)));
typedef unsigned short us4 __attribute__((ext_vector_type(4)));
typedef short s8v __attribute__((ext_vector_type(8)));     // 8 bf16 (4 VGPRs)
typedef float f4 __attribute__((ext_vector_type(4)));      // MFMA acc

constexpr int SH = 9;        // rows per bucket = 512
constexpr int RPB = 1 << SH; // 512
constexpr int NBMAX = 320;   // max buckets (n <= 163840)
constexpr int CHUNK = 6144;  // edges per phase-1 block

__device__ __forceinline__ unsigned short f2bf(float v) {
  unsigned u = __float_as_uint(v);
  return (unsigned short)((u + 0x7fffu + ((u >> 16) & 1u)) >> 16);  // RNE
}

// ---------------------------------------------------------------------------
// k_init: ego -> out cols [0,64) (f32) and bf16 gather table xh (= xh_b).
// ---------------------------------------------------------------------------
__global__ void k_init(const float* __restrict__ ego, float* __restrict__ out,
                       unsigned short* __restrict__ xh, int n) {
  int tid = blockIdx.x * blockDim.x + threadIdx.x;
  int total = n * 16;
  int stride = gridDim.x * blockDim.x;
  for (int t = tid; t < total; t += stride) {
    int r = t >> 4, c = (t & 15) * 4;
    float4 v = *(const float4*)(ego + (size_t)r * 64 + c);
    *(float4*)(out + (size_t)r * 176 + c) = v;
    us4 h;
    h.x = f2bf(v.x); h.y = f2bf(v.y); h.z = f2bf(v.z); h.w = f2bf(v.w);
    *(us4*)(xh + (size_t)r * 64 + c) = h;
  }
}

// ---------------------------------------------------------------------------
// Sort pipeline (proven round 9/13): hist -> scanb -> bucket -> bsort
// ---------------------------------------------------------------------------
__global__ void __launch_bounds__(256) k_hist(const int* __restrict__ erow,
                                              int* __restrict__ bcnt, int E, int nb) {
  __shared__ int h[NBMAX];
  for (int i = threadIdx.x; i < NBMAX; i += 256) h[i] = 0;
  __syncthreads();
  int tid = blockIdx.x * blockDim.x + threadIdx.x;
  int stride = gridDim.x * blockDim.x;
  for (int e = tid; e < E; e += stride) atomicAdd(&h[erow[e] >> SH], 1);
  __syncthreads();
  for (int b = threadIdx.x; b < nb; b += 256)
    if (h[b]) atomicAdd(&bcnt[b], h[b]);
}

__global__ void k_scanb(const int* __restrict__ bcnt, int* __restrict__ boff,
                        int* __restrict__ bcur, int* __restrict__ rp,
                        int nb, int n, int E) {
  int l = threadIdx.x;  // 64 threads
  constexpr int PB = NBMAX / 64;  // 5
  int local[PB];
  int s = 0;
  int base = l * PB;
  for (int j = 0; j < PB; ++j) {
    int b = base + j;
    int c = (b < nb) ? bcnt[b] : 0;
    local[j] = c;
    s += c;
  }
  int incl = s;
  for (int d = 1; d < 64; d <<= 1) {
    int v = __shfl_up(incl, d);
    if (l >= d) incl += v;
  }
  int ex = incl - s;
  for (int j = 0; j < PB; ++j) {
    int b = base + j;
    if (b <= nb) { boff[b] = ex; bcur[b] = ex; }
    ex += local[j];
  }
  if (l == 63) boff[nb] = incl;
  if (l == 0) rp[n] = E;
}

__global__ void __launch_bounds__(256) k_bucket(
    const int* __restrict__ erow, const int* __restrict__ ecol,
    const float* __restrict__ ev, int* __restrict__ bcur,
    int2* __restrict__ bkt, int E, int nb) {
  __shared__ int hist[NBMAX];
  __shared__ int excl[NBMAX + 1];
  __shared__ int curl[NBMAX];
  __shared__ int gbase[NBMAX];
  __shared__ int2 skv[CHUNK];
  int base = blockIdx.x * CHUNK;
  int cnt = min(CHUNK, E - base);

  for (int i = threadIdx.x; i < NBMAX; i += 256) hist[i] = 0;
  __syncthreads();
  for (int i = threadIdx.x; i < cnt; i += 256)
    atomicAdd(&hist[erow[base + i] >> SH], 1);
  __syncthreads();

  if (threadIdx.x < 64) {
    int l = threadIdx.x;
    constexpr int PB = NBMAX / 64;
    int lsum[PB];
    int s = 0;
    for (int j = 0; j < PB; ++j) { lsum[j] = hist[l * PB + j]; s += lsum[j]; }
    int incl = s;
    for (int d = 1; d < 64; d <<= 1) {
      int v = __shfl_up(incl, d);
      if (l >= d) incl += v;
    }
    int ex = incl - s;
    for (int j = 0; j < PB; ++j) { excl[l * PB + j] = ex; ex += lsum[j]; }
    if (l == 63) excl[NBMAX] = incl;
  }
  __syncthreads();

  for (int b = threadIdx.x; b < nb; b += 256) {
    curl[b] = 0;
    int c = hist[b];
    if (c) gbase[b] = atomicAdd(&bcur[b], c);
  }
  __syncthreads();

  for (int i = threadIdx.x; i < cnt; i += 256) {
    int r = erow[base + i];
    int b = r >> SH;
    int lr = r & (RPB - 1);
    int slot = excl[b] + atomicAdd(&curl[b], 1);
    int2 p;
    p.x = (lr << 18) | ecol[base + i];
    p.y = __float_as_int(ev[base + i]);
    skv[slot] = p;
  }
  __syncthreads();

  for (int s = threadIdx.x; s < cnt; s += 256) {
    int lo = 0, hi = nb;
    while (hi - lo > 1) {
      int mid = (lo + hi) >> 1;
      if (excl[mid] <= s) lo = mid; else hi = mid;
    }
    bkt[gbase[lo] + (s - excl[lo])] = skv[s];
  }
}

__global__ void __launch_bounds__(512) k_bsort(
    const int* __restrict__ boff, const int2* __restrict__ bkt,
    int2* __restrict__ cv, int* __restrict__ rp, int n) {
  __shared__ int cnt[RPB];
  __shared__ int sc[RPB];
  __shared__ int exs[RPB];
  __shared__ int cur[RPB];
  int b = blockIdx.x;
  int off = boff[b];
  int m = boff[b + 1] - off;
  int t = threadIdx.x;

  cnt[t] = 0;
  __syncthreads();
  for (int i = t; i < m; i += 512) atomicAdd(&cnt[bkt[off + i].x >> 18], 1);
  __syncthreads();
  sc[t] = cnt[t];
  __syncthreads();
  for (int o = 1; o < RPB; o <<= 1) {
    int v = (t >= o) ? sc[t - o] : 0;
    __syncthreads();
    sc[t] += v;
    __syncthreads();
  }
  int ex = sc[t] - cnt[t];
  exs[t] = ex;
  cur[t] = 0;
  int row = (b << SH) + t;
  if (row < n) rp[row] = off + ex;
  __syncthreads();
  for (int i = t; i < m; i += 512) {
    int2 p = bkt[off + i];
    int lr = p.x >> 18;
    int pos = exs[lr] + atomicAdd(&cur[lr], 1);
    int2 q;
    q.x = p.x & 0x3FFFF;
    q.y = p.y;
    cv[off + pos] = q;
  }
}

// ---------------------------------------------------------------------------
// k_fgx: FUSED gather-SpMM + MFMA transform. Block = 256 thr / 4 waves /
// 64 rows. Phase 1: wave w gathers rows w*16..w*16+15 with the proven
// chunked gather (LPE=DIN/8 lanes x 16B per edge, register accumulation),
// then writes bf16 a/m straight into swizzled LDS tiles sA/sM.
// Phase 2 (after one barrier): proven MFMA transform.
// RACE FIX vs round 15: xhin and xhout are DIFFERENT buffers (ping-pong) —
// a block's epilogue write can no longer collide with another block's
// gather reads in the same dispatch.
// ---------------------------------------------------------------------------
template <int DIN, int DOUT>
__global__ void __launch_bounds__(256, 5) k_fgx(
    const int* __restrict__ rp, const int2* __restrict__ cv,
    const unsigned short* __restrict__ xhin, const float* __restrict__ xin,
    const float* __restrict__ W1, const float* __restrict__ b1,
    const float* __restrict__ W2, const float* __restrict__ b2,
    float* __restrict__ outp, unsigned short* __restrict__ xhout, int n) {
  constexpr int ROWB = DIN * 2;          // LDS row stride (bytes)
  constexpr int RMASK = (ROWB / 16) - 1; // swizzle mask
  constexpr int NTC = DOUT / 16;
  constexpr int LPE = DIN / 8;   // lanes per edge (8 or 4)
  constexpr int EPI = 64 / LPE;  // edges per wave-iter (8 or 16)
  __shared__ unsigned short sA[64 * DIN];
  __shared__ unsigned short sM[64 * DIN];
  __shared__ unsigned short sW1[DOUT * DIN];
  __shared__ unsigned short sW2[DOUT * DIN];

  int tid = threadIdx.x;
  int w = tid >> 6, lane = tid & 63;
  int row0 = blockIdx.x * 64;

  // stage W^T (bf16), row = out col c, contiguous in k (proven k_xf code)
  for (int i = tid; i < DIN * DOUT; i += 256) {
    int k = i / DOUT, c = i - k * DOUT;
    int boffb = c * ROWB + ((k * 2) ^ ((c & RMASK) << 4));
    *(unsigned short*)((char*)sW1 + boffb) = f2bf(W1[i]);
    *(unsigned short*)((char*)sW2 + boffb) = f2bf(W2[i]);
  }

  // ---- phase 1: gather 16 rows per wave (proven r13 chunked loop) ----
  int g = lane / LPE, ch = lane % LPE;
  for (int rr = 0; rr < 16; ++rr) {
    int lr = w * 16 + rr;
    int row = row0 + lr;
    if (row >= n) break;  // wave-uniform
    int beg = rp[row], end = rp[row + 1];

    float acc[8];
#pragma unroll
    for (int j = 0; j < 8; ++j) acc[j] = 0.0f;

    if (beg < end) {
      int2 q = cv[min(beg + g, end - 1)];
      for (int e = beg; e < end; e += EPI) {
        int2 qn = cv[min(e + EPI + g, end - 1)];  // prefetch next iter
        float val = (e + g < end) ? __int_as_float(q.y) : 0.0f;
        s8v xr = *(const s8v*)(xhin + (size_t)(unsigned)q.x * 64 + ch * 8);
#pragma unroll
        for (int j = 0; j < 4; ++j) {
          unsigned d = ((const unsigned*)&xr)[j];
          acc[2 * j] = fmaf(val, __uint_as_float(d << 16), acc[2 * j]);
          acc[2 * j + 1] = fmaf(val, __uint_as_float(d & 0xffff0000u), acc[2 * j + 1]);
        }
        q = qn;
      }
    }
#pragma unroll
    for (int off = LPE; off < 64; off <<= 1) {
#pragma unroll
      for (int j = 0; j < 8; ++j) acc[j] += __shfl_xor(acc[j], off);
    }

    if (lane < LPE) {
      float4 x0 = *(const float4*)(xin + (size_t)row * 176 + ch * 8);
      float4 x1 = *(const float4*)(xin + (size_t)row * 176 + ch * 8 + 4);
      float xa[8] = {x0.x, x0.y, x0.z, x0.w, x1.x, x1.y, x1.z, x1.w};
      unsigned aw[4], mw[4];
#pragma unroll
      for (int j = 0; j < 4; ++j) {
        float a0 = xa[2 * j] + acc[2 * j], a1 = xa[2 * j + 1] + acc[2 * j + 1];
        float m0 = xa[2 * j] * acc[2 * j], m1 = xa[2 * j + 1] * acc[2 * j + 1];
        aw[j] = (unsigned)f2bf(a0) | ((unsigned)f2bf(a1) << 16);
        mw[j] = (unsigned)f2bf(m0) | ((unsigned)f2bf(m1) << 16);
      }
      int boffb = lr * ROWB + ((ch * 16) ^ ((lr & RMASK) << 4));
      *(iv4*)((char*)sA + boffb) = (iv4){(int)aw[0], (int)aw[1], (int)aw[2], (int)aw[3]};
      *(iv4*)((char*)sM + boffb) = (iv4){(int)mw[0], (int)mw[1], (int)mw[2], (int)mw[3]};
    }
  }
  __syncthreads();

  // ---- phase 2: MFMA transform (proven k_xf body) ----
  int l = lane;
  int tr = w;

  f4 acc1[NTC], acc2[NTC];
#pragma unroll
  for (int tc = 0; tc < NTC; ++tc) {
    acc1[tc] = (f4){0.0f, 0.0f, 0.0f, 0.0f};
    acc2[tc] = (f4){0.0f, 0.0f, 0.0f, 0.0f};
  }

#pragma unroll
  for (int k0 = 0; k0 < DIN; k0 += 32) {
    int ra = tr * 16 + (l & 15);
    int inb = (k0 + (l >> 4) * 8) * 2;
    s8v af = *(const s8v*)((const char*)sA + ra * ROWB + (inb ^ ((ra & RMASK) << 4)));
    s8v mf = *(const s8v*)((const char*)sM + ra * ROWB + (inb ^ ((ra & RMASK) << 4)));
#pragma unroll
    for (int tc = 0; tc < NTC; ++tc) {
      int rc = tc * 16 + (l & 15);
      int wb = rc * ROWB + (inb ^ ((rc & RMASK) << 4));
      s8v w1 = *(const s8v*)((const char*)sW1 + wb);
      s8v w2 = *(const s8v*)((const char*)sW2 + wb);
      acc1[tc] = __builtin_amdgcn_mfma_f32_16x16x32_bf16(af, w1, acc1[tc], 0, 0, 0);
      acc2[tc] = __builtin_amdgcn_mfma_f32_16x16x32_bf16(mf, w2, acc2[tc], 0, 0, 0);
    }
  }

#pragma unroll
  for (int tc = 0; tc < NTC; ++tc) {
    int c = tc * 16 + (l & 15);
    float bb1 = b1[c], bb2 = b2[c];
#pragma unroll
    for (int j = 0; j < 4; ++j) {
      int r = tr * 16 + (l >> 4) * 4 + j;
      if (row0 + r < n) {
        float v1 = acc1[tc][j] + bb1;
        float v2 = acc2[tc][j] + bb2;
        float xn = LEAKY(v1) + LEAKY(v2);
        outp[(size_t)(row0 + r) * 176 + c] = xn;
        if (xhout) xhout[(size_t)(row0 + r) * 64 + c] = f2bf(xn);
      }
    }
  }
}

// ---------------------------------------------------------------------------
// k_norm: L2-normalize cols [64,128), [128,160), [160,176) in place.
// ---------------------------------------------------------------------------
__global__ void __launch_bounds__(256) k_norm(float* out, int n) {
  int row = (int)((blockIdx.x * (unsigned)blockDim.x + threadIdx.x) >> 6);
  int lane = threadIdx.x & 63;
  if (row >= n) return;
  float* r = out + (size_t)row * 176;
  float a = r[64 + lane];
  float b = (lane < 48) ? r[128 + lane] : 0.0f;
  float sa = a * a;
  float sb_ = (lane < 32) ? b * b : 0.0f;
  float sc = (lane >= 32 && lane < 48) ? b * b : 0.0f;
#pragma unroll
  for (int off = 32; off; off >>= 1) {
    sa += __shfl_xor(sa, off);
    sb_ += __shfl_xor(sb_, off);
    sc += __shfl_xor(sc, off);
  }
  float ia = 1.0f / fmaxf(sqrtf(sa), 1e-12f);
  float ib = 1.0f / fmaxf(sqrtf(sb_), 1e-12f);
  float ic = 1.0f / fmaxf(sqrtf(sc), 1e-12f);
  r[64 + lane] = a * ia;
  if (lane < 48) r[128 + lane] = b * ((lane < 32) ? ib : ic);
}

// ---------------------------------------------------------------------------
extern "C" void kernel_launch(void* const* d_in, const int* in_sizes, int n_in,
                              void* d_out, int out_size, void* d_ws, size_t ws_size,
                              hipStream_t stream) {
  const float* ego = (const float*)d_in[0];
  const int* erow = (const int*)d_in[1];
  const int* ecol = (const int*)d_in[2];
  const float* ev = (const float*)d_in[3];
  const int n = in_sizes[0] / 64;  // 160000
  const int E = in_sizes[1];       // 5120000
  const int nb = (n + RPB - 1) >> SH;  // 313

  float* out = (float*)d_out;  // [n, 176] f32

  // ws: bkt[E] | cv[E] | rp[n+1] | bcnt | boff | bcur | xh_b[n*64] bf16
  // total ~103.1 MB (proven in rounds 11-13). xh_a (20.5 MB) OVERLAYS bkt,
  // which is dead after k_bsort -> ping-pong eliminates the r15 race.
  int2* bkt = (int2*)d_ws;
  int2* cv = bkt + E;
  int* rp = (int*)(cv + E);
  int* bcnt = rp + n + 1;
  int* boff = bcnt + NBMAX;
  int* bcur = boff + NBMAX + 1;
  unsigned short* xh_b = (unsigned short*)(bcur + NBMAX);
  unsigned short* xh_a = (unsigned short*)d_ws;  // overlay on bkt

  const int rblocks = (n + 3) / 4;   // k_norm: one wave per row
  const int xblocks = (n + 63) / 64; // k_fgx: 64 rows per block

  k_init<<<2048, 256, 0, stream>>>(ego, out, xh_b, n);
  hipMemsetAsync(bcnt, 0, NBMAX * sizeof(int), stream);
  k_hist<<<1024, 256, 0, stream>>>(erow, bcnt, E, nb);
  k_scanb<<<1, 64, 0, stream>>>(bcnt, boff, bcur, rp, nb, n, E);
  k_bucket<<<(E + CHUNK - 1) / CHUNK, 256, 0, stream>>>(erow, ecol, ev, bcur, bkt, E, nb);
  k_bsort<<<nb, 512, 0, stream>>>(boff, bkt, cv, rp, n);
  // bkt dead from here; xh_a takes its space

  const float* W1_0 = (const float*)d_in[4];
  const float* B1_0 = (const float*)d_in[5];
  const float* W2_0 = (const float*)d_in[6];
  const float* B2_0 = (const float*)d_in[7];
  const float* W1_1 = (const float*)d_in[8];
  const float* B1_1 = (const float*)d_in[9];
  const float* W2_1 = (const float*)d_in[10];
  const float* B2_1 = (const float*)d_in[11];
  const float* W1_2 = (const float*)d_in[12];
  const float* B1_2 = (const float*)d_in[13];
  const float* W2_2 = (const float*)d_in[14];
  const float* B2_2 = (const float*)d_in[15];

  k_fgx<64, 64><<<xblocks, 256, 0, stream>>>(
      rp, cv, xh_b, out, W1_0, B1_0, W2_0, B2_0, out + 64, xh_a, n);
  k_fgx<64, 32><<<xblocks, 256, 0, stream>>>(
      rp, cv, xh_a, out + 64, W1_1, B1_1, W2_1, B2_1, out + 128, xh_b, n);
  k_fgx<32, 16><<<xblocks, 256, 0, stream>>>(
      rp, cv, xh_b, out + 128, W1_2, B1_2, W2_2, B2_2, out + 160, nullptr, n);

  k_norm<<<rblocks, 256, 0, stream>>>(out, n);
}

// Round 17
// 776.931 us; speedup vs baseline: 6.8272x; 1.0179x over previous
//
#include <hip/hip_runtime.h>
#include <hip/hip_bf16.h>

#define LEAKY(v) ((v) >= 0.0f ? (v) : 0.01f * (v))

typedef int iv4 __attribute__((ext_vector_type(4)));
typedef unsigned short us4 __attribute__((ext_vector_type(4)));
typedef short s8v __attribute__((ext_vector_type(8)));     // 8 bf16 (4 VGPRs)
typedef float f4 __attribute__((ext_vector_type(4)));      // MFMA acc
typedef float fv8 __attribute__((ext_vector_type(8)));     // 8 f32
typedef unsigned uv8 __attribute__((ext_vector_type(8)));  // 8 u32

constexpr int SH = 9;        // rows per bucket = 512
constexpr int RPB = 1 << SH; // 512
constexpr int NBMAX = 320;   // max buckets (n <= 163840)
constexpr int CHUNK = 6144;  // edges per phase-1 block

__device__ __forceinline__ unsigned short f2bf(float v) {
  unsigned u = __float_as_uint(v);
  return (unsigned short)((u + 0x7fffu + ((u >> 16) & 1u)) >> 16);  // RNE
}

// ---------------------------------------------------------------------------
// k_init: ego -> out cols [0,64) (f32) and bf16 gather table xh.
// ---------------------------------------------------------------------------
__global__ void k_init(const float* __restrict__ ego, float* __restrict__ out,
                       unsigned short* __restrict__ xh, int n) {
  int tid = blockIdx.x * blockDim.x + threadIdx.x;
  int total = n * 16;
  int stride = gridDim.x * blockDim.x;
  for (int t = tid; t < total; t += stride) {
    int r = t >> 4, c = (t & 15) * 4;
    float4 v = *(const float4*)(ego + (size_t)r * 64 + c);
    *(float4*)(out + (size_t)r * 176 + c) = v;
    us4 h;
    h.x = f2bf(v.x); h.y = f2bf(v.y); h.z = f2bf(v.z); h.w = f2bf(v.w);
    *(us4*)(xh + (size_t)r * 64 + c) = h;
  }
}

// ---------------------------------------------------------------------------
// Sort pipeline (proven round 9/13): hist -> scanb -> bucket -> bsort
// ---------------------------------------------------------------------------
__global__ void __launch_bounds__(256) k_hist(const int* __restrict__ erow,
                                              int* __restrict__ bcnt, int E, int nb) {
  __shared__ int h[NBMAX];
  for (int i = threadIdx.x; i < NBMAX; i += 256) h[i] = 0;
  __syncthreads();
  int tid = blockIdx.x * blockDim.x + threadIdx.x;
  int stride = gridDim.x * blockDim.x;
  for (int e = tid; e < E; e += stride) atomicAdd(&h[erow[e] >> SH], 1);
  __syncthreads();
  for (int b = threadIdx.x; b < nb; b += 256)
    if (h[b]) atomicAdd(&bcnt[b], h[b]);
}

__global__ void k_scanb(const int* __restrict__ bcnt, int* __restrict__ boff,
                        int* __restrict__ bcur, int* __restrict__ rp,
                        int nb, int n, int E) {
  int l = threadIdx.x;  // 64 threads
  constexpr int PB = NBMAX / 64;  // 5
  int local[PB];
  int s = 0;
  int base = l * PB;
  for (int j = 0; j < PB; ++j) {
    int b = base + j;
    int c = (b < nb) ? bcnt[b] : 0;
    local[j] = c;
    s += c;
  }
  int incl = s;
  for (int d = 1; d < 64; d <<= 1) {
    int v = __shfl_up(incl, d);
    if (l >= d) incl += v;
  }
  int ex = incl - s;
  for (int j = 0; j < PB; ++j) {
    int b = base + j;
    if (b <= nb) { boff[b] = ex; bcur[b] = ex; }
    ex += local[j];
  }
  if (l == 63) boff[nb] = incl;
  if (l == 0) rp[n] = E;
}

__global__ void __launch_bounds__(256) k_bucket(
    const int* __restrict__ erow, const int* __restrict__ ecol,
    const float* __restrict__ ev, int* __restrict__ bcur,
    int2* __restrict__ bkt, int E, int nb) {
  __shared__ int hist[NBMAX];
  __shared__ int excl[NBMAX + 1];
  __shared__ int curl[NBMAX];
  __shared__ int gbase[NBMAX];
  __shared__ int2 skv[CHUNK];
  int base = blockIdx.x * CHUNK;
  int cnt = min(CHUNK, E - base);

  for (int i = threadIdx.x; i < NBMAX; i += 256) hist[i] = 0;
  __syncthreads();
  for (int i = threadIdx.x; i < cnt; i += 256)
    atomicAdd(&hist[erow[base + i] >> SH], 1);
  __syncthreads();

  if (threadIdx.x < 64) {
    int l = threadIdx.x;
    constexpr int PB = NBMAX / 64;
    int lsum[PB];
    int s = 0;
    for (int j = 0; j < PB; ++j) { lsum[j] = hist[l * PB + j]; s += lsum[j]; }
    int incl = s;
    for (int d = 1; d < 64; d <<= 1) {
      int v = __shfl_up(incl, d);
      if (l >= d) incl += v;
    }
    int ex = incl - s;
    for (int j = 0; j < PB; ++j) { excl[l * PB + j] = ex; ex += lsum[j]; }
    if (l == 63) excl[NBMAX] = incl;
  }
  __syncthreads();

  for (int b = threadIdx.x; b < nb; b += 256) {
    curl[b] = 0;
    int c = hist[b];
    if (c) gbase[b] = atomicAdd(&bcur[b], c);
  }
  __syncthreads();

  for (int i = threadIdx.x; i < cnt; i += 256) {
    int r = erow[base + i];
    int b = r >> SH;
    int lr = r & (RPB - 1);
    int slot = excl[b] + atomicAdd(&curl[b], 1);
    int2 p;
    p.x = (lr << 18) | ecol[base + i];
    p.y = __float_as_int(ev[base + i]);
    skv[slot] = p;
  }
  __syncthreads();

  for (int s = threadIdx.x; s < cnt; s += 256) {
    int lo = 0, hi = nb;
    while (hi - lo > 1) {
      int mid = (lo + hi) >> 1;
      if (excl[mid] <= s) lo = mid; else hi = mid;
    }
    bkt[gbase[lo] + (s - excl[lo])] = skv[s];
  }
}

__global__ void __launch_bounds__(512) k_bsort(
    const int* __restrict__ boff, const int2* __restrict__ bkt,
    int2* __restrict__ cv, int* __restrict__ rp, int n) {
  __shared__ int cnt[RPB];
  __shared__ int sc[RPB];
  __shared__ int exs[RPB];
  __shared__ int cur[RPB];
  int b = blockIdx.x;
  int off = boff[b];
  int m = boff[b + 1] - off;
  int t = threadIdx.x;

  cnt[t] = 0;
  __syncthreads();
  for (int i = t; i < m; i += 512) atomicAdd(&cnt[bkt[off + i].x >> 18], 1);
  __syncthreads();
  sc[t] = cnt[t];
  __syncthreads();
  for (int o = 1; o < RPB; o <<= 1) {
    int v = (t >= o) ? sc[t - o] : 0;
    __syncthreads();
    sc[t] += v;
    __syncthreads();
  }
  int ex = sc[t] - cnt[t];
  exs[t] = ex;
  cur[t] = 0;
  int row = (b << SH) + t;
  if (row < n) rp[row] = off + ex;
  __syncthreads();
  for (int i = t; i < m; i += 512) {
    int2 p = bkt[off + i];
    int lr = p.x >> 18;
    int pos = exs[lr] + atomicAdd(&cur[lr], 1);
    int2 q;
    q.x = p.x & 0x3FFFF;
    q.y = p.y;
    cv[off + pos] = q;
  }
}

// ---------------------------------------------------------------------------
// k_gam: gather-only SpMM, CHUNKED (proven r13): each edge handled by
// LPE=DIN/8 lanes, each lane gathers a 16B chunk (8 bf16) of xh[col].
// amp[row][f] = bf16(a) | bf16(m)<<16.
// ---------------------------------------------------------------------------
template <int DIN, bool BF>
__global__ void __launch_bounds__(256, 8) k_gam(
    const int* __restrict__ rp, const int2* __restrict__ cv,
    const unsigned short* __restrict__ xh, const float* __restrict__ xin,
    unsigned* __restrict__ amp, int n) {
  int row = (int)((blockIdx.x * (unsigned)blockDim.x + threadIdx.x) >> 6);
  int lane = threadIdx.x & 63;
  if (row >= n) return;

  int beg = rp[row], end = rp[row + 1];

  if constexpr (BF) {
    constexpr int LPE = DIN / 8;   // lanes per edge (8 or 4)
    constexpr int EPI = 64 / LPE;  // edges per iteration (8 or 16)
    int eg = lane / LPE;           // edge slot
    int ch = lane % LPE;           // 16B chunk index

    float acc[8];
#pragma unroll
    for (int j = 0; j < 8; ++j) acc[j] = 0.0f;

    if (beg < end) {
      int2 q = cv[min(beg + eg, end - 1)];
      for (int e = beg; e < end; e += EPI) {
        int2 qn = cv[min(e + EPI + eg, end - 1)];  // prefetch next iter
        float val = (e + eg < end) ? __int_as_float(q.y) : 0.0f;
        s8v xr = *(const s8v*)(xh + (size_t)(unsigned)q.x * 64 + ch * 8);
#pragma unroll
        for (int j = 0; j < 4; ++j) {
          unsigned d = ((const unsigned*)&xr)[j];
          acc[2 * j] = fmaf(val, __uint_as_float(d << 16), acc[2 * j]);
          acc[2 * j + 1] = fmaf(val, __uint_as_float(d & 0xffff0000u), acc[2 * j + 1]);
        }
        q = qn;
      }
    }

#pragma unroll
    for (int off = LPE; off < 64; off <<= 1) {
#pragma unroll
      for (int j = 0; j < 8; ++j) acc[j] += __shfl_xor(acc[j], off);
    }

    if (lane < LPE) {
      fv8 xv = *(const fv8*)(xin + (size_t)row * 176 + lane * 8);
      uv8 w;
#pragma unroll
      for (int j = 0; j < 8; ++j) {
        float a = xv[j] + acc[j];
        float m = xv[j] * acc[j];
        w[j] = (unsigned)f2bf(a) | ((unsigned)f2bf(m) << 16);
      }
      *(uv8*)(amp + (size_t)row * 64 + lane * 8) = w;
    }
  } else {
    // fallback: per-lane scalar f32 gather (proven round-9 path)
    int f = lane & (DIN - 1);
    float xv = (lane < DIN) ? xin[(size_t)row * 176 + lane] : 0.0f;
    float acc = 0.0f;
    int e = beg;
    if ((e & 1) && e < end) {
      int2 q = cv[e];
      acc = fmaf(__int_as_float(q.y), xin[(size_t)(unsigned)q.x * 176 + f], acc);
      ++e;
    }
    for (; e + 2 <= end; e += 2) {
      iv4 a = *(const iv4*)(cv + e);
      float g0 = xin[(size_t)(unsigned)a.x * 176 + f];
      float g1 = xin[(size_t)(unsigned)a.z * 176 + f];
      acc = fmaf(__int_as_float(a.y), g0, acc);
      acc = fmaf(__int_as_float(a.w), g1, acc);
    }
    if (e < end) {
      int2 q = cv[e];
      acc = fmaf(__int_as_float(q.y), xin[(size_t)(unsigned)q.x * 176 + f], acc);
    }
    if (lane < DIN) {
      float a = xv + acc, m = xv * acc;
      amp[(size_t)row * 64 + lane] = (unsigned)f2bf(a) | ((unsigned)f2bf(m) << 16);
    }
  }
}

// ---------------------------------------------------------------------------
// k_xf: MFMA transform (proven r13). Block = 64 rows, 4 waves.
//   xn = leaky(A@W1 + b1) + leaky(M@W2 + b2)
// A/M and transposed W1/W2 staged in XOR-swizzled LDS.
// Writes f32 out (+ bf16 gather table xh for the next layer, if non-null).
// ---------------------------------------------------------------------------
template <int DIN, int DOUT>
__global__ void __launch_bounds__(256) k_xf(
    const unsigned* __restrict__ amp,
    const float* __restrict__ W1, const float* __restrict__ b1,
    const float* __restrict__ W2, const float* __restrict__ b2,
    float* __restrict__ outp, unsigned short* __restrict__ xh, int n) {
  constexpr int ROWB = DIN * 2;          // LDS row stride (bytes)
  constexpr int RMASK = (ROWB / 16) - 1; // swizzle mask
  constexpr int NTC = DOUT / 16;
  __shared__ unsigned short sA[64 * DIN];
  __shared__ unsigned short sM[64 * DIN];
  __shared__ unsigned short sW1[DOUT * DIN];
  __shared__ unsigned short sW2[DOUT * DIN];

  int row0 = blockIdx.x * 64;

  constexpr int PAIRS = DIN / 2;
  for (int i = threadIdx.x; i < 64 * PAIRS; i += 256) {
    int r = i / PAIRS, fp = (i - r * PAIRS) * 2;
    unsigned lo = 0, hi = 0;
    if (row0 + r < n) {
      uint2 q = *(const uint2*)(amp + (size_t)(row0 + r) * 64 + fp);
      lo = (q.x & 0xffffu) | ((q.y & 0xffffu) << 16);  // a pair
      hi = (q.x >> 16) | (q.y & 0xffff0000u);          // m pair
    }
    int boffb = r * ROWB + ((fp * 2) ^ ((r & RMASK) << 4));
    *(unsigned*)((char*)sA + boffb) = lo;
    *(unsigned*)((char*)sM + boffb) = hi;
  }
  for (int i = threadIdx.x; i < DIN * DOUT; i += 256) {
    int k = i / DOUT, c = i - k * DOUT;
    int boffb = c * ROWB + ((k * 2) ^ ((c & RMASK) << 4));
    *(unsigned short*)((char*)sW1 + boffb) = f2bf(W1[i]);
    *(unsigned short*)((char*)sW2 + boffb) = f2bf(W2[i]);
  }
  __syncthreads();

  int w = threadIdx.x >> 6, l = threadIdx.x & 63;
  int tr = w;

  f4 acc1[NTC], acc2[NTC];
#pragma unroll
  for (int tc = 0; tc < NTC; ++tc) {
    acc1[tc] = (f4){0.0f, 0.0f, 0.0f, 0.0f};
    acc2[tc] = (f4){0.0f, 0.0f, 0.0f, 0.0f};
  }

#pragma unroll
  for (int k0 = 0; k0 < DIN; k0 += 32) {
    int ra = tr * 16 + (l & 15);
    int inb = (k0 + (l >> 4) * 8) * 2;
    s8v af = *(const s8v*)((const char*)sA + ra * ROWB + (inb ^ ((ra & RMASK) << 4)));
    s8v mf = *(const s8v*)((const char*)sM + ra * ROWB + (inb ^ ((ra & RMASK) << 4)));
#pragma unroll
    for (int tc = 0; tc < NTC; ++tc) {
      int rc = tc * 16 + (l & 15);
      int wb = rc * ROWB + (inb ^ ((rc & RMASK) << 4));
      s8v w1 = *(const s8v*)((const char*)sW1 + wb);
      s8v w2 = *(const s8v*)((const char*)sW2 + wb);
      acc1[tc] = __builtin_amdgcn_mfma_f32_16x16x32_bf16(af, w1, acc1[tc], 0, 0, 0);
      acc2[tc] = __builtin_amdgcn_mfma_f32_16x16x32_bf16(mf, w2, acc2[tc], 0, 0, 0);
    }
  }

#pragma unroll
  for (int tc = 0; tc < NTC; ++tc) {
    int c = tc * 16 + (l & 15);
    float bb1 = b1[c], bb2 = b2[c];
#pragma unroll
    for (int j = 0; j < 4; ++j) {
      int r = tr * 16 + (l >> 4) * 4 + j;
      if (row0 + r < n) {
        float v1 = acc1[tc][j] + bb1;
        float v2 = acc2[tc][j] + bb2;
        float xn = LEAKY(v1) + LEAKY(v2);
        outp[(size_t)(row0 + r) * 176 + c] = xn;
        if (xh) xh[(size_t)(row0 + r) * 64 + c] = f2bf(xn);
      }
    }
  }
}

// ---------------------------------------------------------------------------
// k_fgx: FUSED gather+MFMA (proven r16) — used for the DIN=32 layer only,
// where per-row loop overhead dominates and fusion wins. Reads xhin
// (written by the previous dispatch), writes no gather table -> race-free.
// ---------------------------------------------------------------------------
template <int DIN, int DOUT>
__global__ void __launch_bounds__(256, 5) k_fgx(
    const int* __restrict__ rp, const int2* __restrict__ cv,
    const unsigned short* __restrict__ xhin, const float* __restrict__ xin,
    const float* __restrict__ W1, const float* __restrict__ b1,
    const float* __restrict__ W2, const float* __restrict__ b2,
    float* __restrict__ outp, unsigned short* __restrict__ xhout, int n) {
  constexpr int ROWB = DIN * 2;
  constexpr int RMASK = (ROWB / 16) - 1;
  constexpr int NTC = DOUT / 16;
  constexpr int LPE = DIN / 8;
  constexpr int EPI = 64 / LPE;
  __shared__ unsigned short sA[64 * DIN];
  __shared__ unsigned short sM[64 * DIN];
  __shared__ unsigned short sW1[DOUT * DIN];
  __shared__ unsigned short sW2[DOUT * DIN];

  int tid = threadIdx.x;
  int w = tid >> 6, lane = tid & 63;
  int row0 = blockIdx.x * 64;

  for (int i = tid; i < DIN * DOUT; i += 256) {
    int k = i / DOUT, c = i - k * DOUT;
    int boffb = c * ROWB + ((k * 2) ^ ((c & RMASK) << 4));
    *(unsigned short*)((char*)sW1 + boffb) = f2bf(W1[i]);
    *(unsigned short*)((char*)sW2 + boffb) = f2bf(W2[i]);
  }

  int g = lane / LPE, ch = lane % LPE;
  for (int rr = 0; rr < 16; ++rr) {
    int lr = w * 16 + rr;
    int row = row0 + lr;
    if (row >= n) break;  // wave-uniform
    int beg = rp[row], end = rp[row + 1];

    float acc[8];
#pragma unroll
    for (int j = 0; j < 8; ++j) acc[j] = 0.0f;

    if (beg < end) {
      int2 q = cv[min(beg + g, end - 1)];
      for (int e = beg; e < end; e += EPI) {
        int2 qn = cv[min(e + EPI + g, end - 1)];
        float val = (e + g < end) ? __int_as_float(q.y) : 0.0f;
        s8v xr = *(const s8v*)(xhin + (size_t)(unsigned)q.x * 64 + ch * 8);
#pragma unroll
        for (int j = 0; j < 4; ++j) {
          unsigned d = ((const unsigned*)&xr)[j];
          acc[2 * j] = fmaf(val, __uint_as_float(d << 16), acc[2 * j]);
          acc[2 * j + 1] = fmaf(val, __uint_as_float(d & 0xffff0000u), acc[2 * j + 1]);
        }
        q = qn;
      }
    }
#pragma unroll
    for (int off = LPE; off < 64; off <<= 1) {
#pragma unroll
      for (int j = 0; j < 8; ++j) acc[j] += __shfl_xor(acc[j], off);
    }

    if (lane < LPE) {
      float4 x0 = *(const float4*)(xin + (size_t)row * 176 + ch * 8);
      float4 x1 = *(const float4*)(xin + (size_t)row * 176 + ch * 8 + 4);
      float xa[8] = {x0.x, x0.y, x0.z, x0.w, x1.x, x1.y, x1.z, x1.w};
      unsigned aw[4], mw[4];
#pragma unroll
      for (int j = 0; j < 4; ++j) {
        float a0 = xa[2 * j] + acc[2 * j], a1 = xa[2 * j + 1] + acc[2 * j + 1];
        float m0 = xa[2 * j] * acc[2 * j], m1 = xa[2 * j + 1] * acc[2 * j + 1];
        aw[j] = (unsigned)f2bf(a0) | ((unsigned)f2bf(a1) << 16);
        mw[j] = (unsigned)f2bf(m0) | ((unsigned)f2bf(m1) << 16);
      }
      int boffb = lr * ROWB + ((ch * 16) ^ ((lr & RMASK) << 4));
      *(iv4*)((char*)sA + boffb) = (iv4){(int)aw[0], (int)aw[1], (int)aw[2], (int)aw[3]};
      *(iv4*)((char*)sM + boffb) = (iv4){(int)mw[0], (int)mw[1], (int)mw[2], (int)mw[3]};
    }
  }
  __syncthreads();

  int l = lane;
  int tr = w;

  f4 acc1[NTC], acc2[NTC];
#pragma unroll
  for (int tc = 0; tc < NTC; ++tc) {
    acc1[tc] = (f4){0.0f, 0.0f, 0.0f, 0.0f};
    acc2[tc] = (f4){0.0f, 0.0f, 0.0f, 0.0f};
  }

#pragma unroll
  for (int k0 = 0; k0 < DIN; k0 += 32) {
    int ra = tr * 16 + (l & 15);
    int inb = (k0 + (l >> 4) * 8) * 2;
    s8v af = *(const s8v*)((const char*)sA + ra * ROWB + (inb ^ ((ra & RMASK) << 4)));
    s8v mf = *(const s8v*)((const char*)sM + ra * ROWB + (inb ^ ((ra & RMASK) << 4)));
#pragma unroll
    for (int tc = 0; tc < NTC; ++tc) {
      int rc = tc * 16 + (l & 15);
      int wb = rc * ROWB + (inb ^ ((rc & RMASK) << 4));
      s8v w1 = *(const s8v*)((const char*)sW1 + wb);
      s8v w2 = *(const s8v*)((const char*)sW2 + wb);
      acc1[tc] = __builtin_amdgcn_mfma_f32_16x16x32_bf16(af, w1, acc1[tc], 0, 0, 0);
      acc2[tc] = __builtin_amdgcn_mfma_f32_16x16x32_bf16(mf, w2, acc2[tc], 0, 0, 0);
    }
  }

#pragma unroll
  for (int tc = 0; tc < NTC; ++tc) {
    int c = tc * 16 + (l & 15);
    float bb1 = b1[c], bb2 = b2[c];
#pragma unroll
    for (int j = 0; j < 4; ++j) {
      int r = tr * 16 + (l >> 4) * 4 + j;
      if (row0 + r < n) {
        float v1 = acc1[tc][j] + bb1;
        float v2 = acc2[tc][j] + bb2;
        float xn = LEAKY(v1) + LEAKY(v2);
        outp[(size_t)(row0 + r) * 176 + c] = xn;
        if (xhout) xhout[(size_t)(row0 + r) * 64 + c] = f2bf(xn);
      }
    }
  }
}

// ---------------------------------------------------------------------------
// k_norm: L2-normalize cols [64,128), [128,160), [160,176) in place.
// ---------------------------------------------------------------------------
__global__ void __launch_bounds__(256) k_norm(float* out, int n) {
  int row = (int)((blockIdx.x * (unsigned)blockDim.x + threadIdx.x) >> 6);
  int lane = threadIdx.x & 63;
  if (row >= n) return;
  float* r = out + (size_t)row * 176;
  float a = r[64 + lane];
  float b = (lane < 48) ? r[128 + lane] : 0.0f;
  float sa = a * a;
  float sb_ = (lane < 32) ? b * b : 0.0f;
  float sc = (lane >= 32 && lane < 48) ? b * b : 0.0f;
#pragma unroll
  for (int off = 32; off; off >>= 1) {
    sa += __shfl_xor(sa, off);
    sb_ += __shfl_xor(sb_, off);
    sc += __shfl_xor(sc, off);
  }
  float ia = 1.0f / fmaxf(sqrtf(sa), 1e-12f);
  float ib = 1.0f / fmaxf(sqrtf(sb_), 1e-12f);
  float ic = 1.0f / fmaxf(sqrtf(sc), 1e-12f);
  r[64 + lane] = a * ia;
  if (lane < 48) r[128 + lane] = b * ((lane < 32) ? ib : ic);
}

// ---------------------------------------------------------------------------
extern "C" void kernel_launch(void* const* d_in, const int* in_sizes, int n_in,
                              void* d_out, int out_size, void* d_ws, size_t ws_size,
                              hipStream_t stream) {
  const float* ego = (const float*)d_in[0];
  const int* erow = (const int*)d_in[1];
  const int* ecol = (const int*)d_in[2];
  const float* ev = (const float*)d_in[3];
  const int n = in_sizes[0] / 64;  // 160000
  const int E = in_sizes[1];       // 5120000
  const int nb = (n + RPB - 1) >> SH;  // 313

  float* out = (float*)d_out;  // [n, 176] f32

  // ws: bkt[E] (amp overlays) | cv[E] | rp[n+1] | meta | xh[n*64] bf16
  // total ~103.1 MB (proven in rounds 11-13, 16)
  int2* bkt = (int2*)d_ws;
  int2* cv = bkt + E;
  int* rp = (int*)(cv + E);
  int* bcnt = rp + n + 1;
  int* boff = bcnt + NBMAX;
  int* bcur = boff + NBMAX + 1;
  unsigned short* xh = (unsigned short*)(bcur + NBMAX);
  unsigned* amp = (unsigned*)d_ws;  // overlays bkt (dead after k_bsort)

  size_t need_bf = (size_t)((char*)(xh + (size_t)n * 64) - (char*)d_ws);
  bool bf = ws_size >= need_bf;

  const int rblocks = (n + 3) / 4;   // one wave per row
  const int xblocks = (n + 63) / 64; // 64 rows per block

  k_init<<<2048, 256, 0, stream>>>(ego, out, bf ? xh : (unsigned short*)d_ws, n);
  hipMemsetAsync(bcnt, 0, NBMAX * sizeof(int), stream);
  k_hist<<<1024, 256, 0, stream>>>(erow, bcnt, E, nb);
  k_scanb<<<1, 64, 0, stream>>>(bcnt, boff, bcur, rp, nb, n, E);
  k_bucket<<<(E + CHUNK - 1) / CHUNK, 256, 0, stream>>>(erow, ecol, ev, bcur, bkt, E, nb);
  k_bsort<<<nb, 512, 0, stream>>>(boff, bkt, cv, rp, n);
  // bkt dead from here; amp takes its space

  const float* W1_0 = (const float*)d_in[4];
  const float* B1_0 = (const float*)d_in[5];
  const float* W2_0 = (const float*)d_in[6];
  const float* B2_0 = (const float*)d_in[7];
  const float* W1_1 = (const float*)d_in[8];
  const float* B1_1 = (const float*)d_in[9];
  const float* W2_1 = (const float*)d_in[10];
  const float* B2_1 = (const float*)d_in[11];
  const float* W1_2 = (const float*)d_in[12];
  const float* B1_2 = (const float*)d_in[13];
  const float* W2_2 = (const float*)d_in[14];
  const float* B2_2 = (const float*)d_in[15];

  if (bf) {
    // layers 0/1: split (proven fastest for DIN=64); layer 2: fused.
    k_gam<64, true><<<rblocks, 256, 0, stream>>>(rp, cv, xh, out, amp, n);
    k_xf<64, 64><<<xblocks, 256, 0, stream>>>(amp, W1_0, B1_0, W2_0, B2_0, out + 64, xh, n);
    k_gam<64, true><<<rblocks, 256, 0, stream>>>(rp, cv, xh, out + 64, amp, n);
    k_xf<64, 32><<<xblocks, 256, 0, stream>>>(amp, W1_1, B1_1, W2_1, B2_1, out + 128, xh, n);
    k_fgx<32, 16><<<xblocks, 256, 0, stream>>>(
        rp, cv, xh, out + 128, W1_2, B1_2, W2_2, B2_2, out + 160, nullptr, n);
  } else {
    k_gam<64, false><<<rblocks, 256, 0, stream>>>(rp, cv, nullptr, out, amp, n);
    k_xf<64, 64><<<xblocks, 256, 0, stream>>>(amp, W1_0, B1_0, W2_0, B2_0, out + 64, nullptr, n);
    k_gam<64, false><<<rblocks, 256, 0, stream>>>(rp, cv, nullptr, out + 64, amp, n);
    k_xf<64, 32><<<xblocks, 256, 0, stream>>>(amp, W1_1, B1_1, W2_1, B2_1, out + 128, nullptr, n);
    k_gam<32, false><<<rblocks, 256, 0, stream>>>(rp, cv, nullptr, out + 128, amp, n);
    k_xf<32, 16><<<xblocks, 256, 0, stream>>>(amp, W1_2, B1_2, W2_2, B2_2, out + 160, nullptr, n);
  }

  k_norm<<<rblocks, 256, 0, stream>>>(out, n);
}

// Round 18
// 760.451 us; speedup vs baseline: 6.9752x; 1.0217x over previous
//
#include <hip/hip_runtime.h>
#include <hip/hip_bf16.h>

#define LEAKY(v) ((v) >= 0.0f ? (v) : 0.01f * (v))

typedef int iv4 __attribute__((ext_vector_type(4)));
typedef unsigned short us4 __attribute__((ext_vector_type(4)));
typedef short s8v __attribute__((ext_vector_type(8)));     // 8 bf16 (4 VGPRs)
typedef float f4 __attribute__((ext_vector_type(4)));      // MFMA acc
typedef float fv8 __attribute__((ext_vector_type(8)));     // 8 f32
typedef unsigned uv8 __attribute__((ext_vector_type(8)));  // 8 u32

constexpr int SH = 9;        // rows per bucket = 512
constexpr int RPB = 1 << SH; // 512
constexpr int NBMAX = 320;   // max buckets (n <= 163840)
constexpr int CHUNK = 6144;  // edges per phase-1 block

__device__ __forceinline__ unsigned short f2bf(float v) {
  unsigned u = __float_as_uint(v);
  return (unsigned short)((u + 0x7fffu + ((u >> 16) & 1u)) >> 16);  // RNE
}

// ---------------------------------------------------------------------------
// k_init: ego -> out cols [0,64) (f32) and bf16 gather table xh.
// ---------------------------------------------------------------------------
__global__ void k_init(const float* __restrict__ ego, float* __restrict__ out,
                       unsigned short* __restrict__ xh, int n) {
  int tid = blockIdx.x * blockDim.x + threadIdx.x;
  int total = n * 16;
  int stride = gridDim.x * blockDim.x;
  for (int t = tid; t < total; t += stride) {
    int r = t >> 4, c = (t & 15) * 4;
    float4 v = *(const float4*)(ego + (size_t)r * 64 + c);
    *(float4*)(out + (size_t)r * 176 + c) = v;
    us4 h;
    h.x = f2bf(v.x); h.y = f2bf(v.y); h.z = f2bf(v.z); h.w = f2bf(v.w);
    *(us4*)(xh + (size_t)r * 64 + c) = h;
  }
}

// ---------------------------------------------------------------------------
// Sort pipeline (proven round 9/13): hist -> scanb -> bucket -> bsort
// ---------------------------------------------------------------------------
__global__ void __launch_bounds__(256) k_hist(const int* __restrict__ erow,
                                              int* __restrict__ bcnt, int E, int nb) {
  __shared__ int h[NBMAX];
  for (int i = threadIdx.x; i < NBMAX; i += 256) h[i] = 0;
  __syncthreads();
  int tid = blockIdx.x * blockDim.x + threadIdx.x;
  int stride = gridDim.x * blockDim.x;
  for (int e = tid; e < E; e += stride) atomicAdd(&h[erow[e] >> SH], 1);
  __syncthreads();
  for (int b = threadIdx.x; b < nb; b += 256)
    if (h[b]) atomicAdd(&bcnt[b], h[b]);
}

__global__ void k_scanb(const int* __restrict__ bcnt, int* __restrict__ boff,
                        int* __restrict__ bcur, int* __restrict__ rp,
                        int nb, int n, int E) {
  int l = threadIdx.x;  // 64 threads
  constexpr int PB = NBMAX / 64;  // 5
  int local[PB];
  int s = 0;
  int base = l * PB;
  for (int j = 0; j < PB; ++j) {
    int b = base + j;
    int c = (b < nb) ? bcnt[b] : 0;
    local[j] = c;
    s += c;
  }
  int incl = s;
  for (int d = 1; d < 64; d <<= 1) {
    int v = __shfl_up(incl, d);
    if (l >= d) incl += v;
  }
  int ex = incl - s;
  for (int j = 0; j < PB; ++j) {
    int b = base + j;
    if (b <= nb) { boff[b] = ex; bcur[b] = ex; }
    ex += local[j];
  }
  if (l == 63) boff[nb] = incl;
  if (l == 0) rp[n] = E;
}

__global__ void __launch_bounds__(256) k_bucket(
    const int* __restrict__ erow, const int* __restrict__ ecol,
    const float* __restrict__ ev, int* __restrict__ bcur,
    int2* __restrict__ bkt, int E, int nb) {
  __shared__ int hist[NBMAX];
  __shared__ int excl[NBMAX + 1];
  __shared__ int curl[NBMAX];
  __shared__ int gbase[NBMAX];
  __shared__ int2 skv[CHUNK];
  int base = blockIdx.x * CHUNK;
  int cnt = min(CHUNK, E - base);

  for (int i = threadIdx.x; i < NBMAX; i += 256) hist[i] = 0;
  __syncthreads();
  for (int i = threadIdx.x; i < cnt; i += 256)
    atomicAdd(&hist[erow[base + i] >> SH], 1);
  __syncthreads();

  if (threadIdx.x < 64) {
    int l = threadIdx.x;
    constexpr int PB = NBMAX / 64;
    int lsum[PB];
    int s = 0;
    for (int j = 0; j < PB; ++j) { lsum[j] = hist[l * PB + j]; s += lsum[j]; }
    int incl = s;
    for (int d = 1; d < 64; d <<= 1) {
      int v = __shfl_up(incl, d);
      if (l >= d) incl += v;
    }
    int ex = incl - s;
    for (int j = 0; j < PB; ++j) { excl[l * PB + j] = ex; ex += lsum[j]; }
    if (l == 63) excl[NBMAX] = incl;
  }
  __syncthreads();

  for (int b = threadIdx.x; b < nb; b += 256) {
    curl[b] = 0;
    int c = hist[b];
    if (c) gbase[b] = atomicAdd(&bcur[b], c);
  }
  __syncthreads();

  for (int i = threadIdx.x; i < cnt; i += 256) {
    int r = erow[base + i];
    int b = r >> SH;
    int lr = r & (RPB - 1);
    int slot = excl[b] + atomicAdd(&curl[b], 1);
    int2 p;
    p.x = (lr << 18) | ecol[base + i];
    p.y = __float_as_int(ev[base + i]);
    skv[slot] = p;
  }
  __syncthreads();

  for (int s = threadIdx.x; s < cnt; s += 256) {
    int lo = 0, hi = nb;
    while (hi - lo > 1) {
      int mid = (lo + hi) >> 1;
      if (excl[mid] <= s) lo = mid; else hi = mid;
    }
    bkt[gbase[lo] + (s - excl[lo])] = skv[s];
  }
}

__global__ void __launch_bounds__(512) k_bsort(
    const int* __restrict__ boff, const int2* __restrict__ bkt,
    int2* __restrict__ cv, int* __restrict__ rp, int n) {
  __shared__ int cnt[RPB];
  __shared__ int sc[RPB];
  __shared__ int exs[RPB];
  __shared__ int cur[RPB];
  int b = blockIdx.x;
  int off = boff[b];
  int m = boff[b + 1] - off;
  int t = threadIdx.x;

  cnt[t] = 0;
  __syncthreads();
  for (int i = t; i < m; i += 512) atomicAdd(&cnt[bkt[off + i].x >> 18], 1);
  __syncthreads();
  sc[t] = cnt[t];
  __syncthreads();
  for (int o = 1; o < RPB; o <<= 1) {
    int v = (t >= o) ? sc[t - o] : 0;
    __syncthreads();
    sc[t] += v;
    __syncthreads();
  }
  int ex = sc[t] - cnt[t];
  exs[t] = ex;
  cur[t] = 0;
  int row = (b << SH) + t;
  if (row < n) rp[row] = off + ex;
  __syncthreads();
  for (int i = t; i < m; i += 512) {
    int2 p = bkt[off + i];
    int lr = p.x >> 18;
    int pos = exs[lr] + atomicAdd(&cur[lr], 1);
    int2 q;
    q.x = p.x & 0x3FFFF;
    q.y = p.y;
    cv[off + pos] = q;
  }
}

// ---------------------------------------------------------------------------
// k_gam: gather-only SpMM, CHUNKED (proven r13): each edge handled by
// LPE=DIN/8 lanes, each lane gathers a 16B chunk (8 bf16) of xh[col].
// amp[row][f] = bf16(a) | bf16(m)<<16.
// ---------------------------------------------------------------------------
template <int DIN, bool BF>
__global__ void __launch_bounds__(256, 8) k_gam(
    const int* __restrict__ rp, const int2* __restrict__ cv,
    const unsigned short* __restrict__ xh, const float* __restrict__ xin,
    unsigned* __restrict__ amp, int n) {
  int row = (int)((blockIdx.x * (unsigned)blockDim.x + threadIdx.x) >> 6);
  int lane = threadIdx.x & 63;
  if (row >= n) return;

  int beg = rp[row], end = rp[row + 1];

  if constexpr (BF) {
    constexpr int LPE = DIN / 8;   // lanes per edge (8 or 4)
    constexpr int EPI = 64 / LPE;  // edges per iteration (8 or 16)
    int eg = lane / LPE;           // edge slot
    int ch = lane % LPE;           // 16B chunk index

    float acc[8];
#pragma unroll
    for (int j = 0; j < 8; ++j) acc[j] = 0.0f;

    if (beg < end) {
      int2 q = cv[min(beg + eg, end - 1)];
      for (int e = beg; e < end; e += EPI) {
        int2 qn = cv[min(e + EPI + eg, end - 1)];  // prefetch next iter
        float val = (e + eg < end) ? __int_as_float(q.y) : 0.0f;
        s8v xr = *(const s8v*)(xh + (size_t)(unsigned)q.x * 64 + ch * 8);
#pragma unroll
        for (int j = 0; j < 4; ++j) {
          unsigned d = ((const unsigned*)&xr)[j];
          acc[2 * j] = fmaf(val, __uint_as_float(d << 16), acc[2 * j]);
          acc[2 * j + 1] = fmaf(val, __uint_as_float(d & 0xffff0000u), acc[2 * j + 1]);
        }
        q = qn;
      }
    }

#pragma unroll
    for (int off = LPE; off < 64; off <<= 1) {
#pragma unroll
      for (int j = 0; j < 8; ++j) acc[j] += __shfl_xor(acc[j], off);
    }

    if (lane < LPE) {
      fv8 xv = *(const fv8*)(xin + (size_t)row * 176 + lane * 8);
      uv8 w;
#pragma unroll
      for (int j = 0; j < 8; ++j) {
        float a = xv[j] + acc[j];
        float m = xv[j] * acc[j];
        w[j] = (unsigned)f2bf(a) | ((unsigned)f2bf(m) << 16);
      }
      *(uv8*)(amp + (size_t)row * 64 + lane * 8) = w;
    }
  } else {
    // fallback: per-lane scalar f32 gather (proven round-9 path)
    int f = lane & (DIN - 1);
    float xv = (lane < DIN) ? xin[(size_t)row * 176 + lane] : 0.0f;
    float acc = 0.0f;
    int e = beg;
    if ((e & 1) && e < end) {
      int2 q = cv[e];
      acc = fmaf(__int_as_float(q.y), xin[(size_t)(unsigned)q.x * 176 + f], acc);
      ++e;
    }
    for (; e + 2 <= end; e += 2) {
      iv4 a = *(const iv4*)(cv + e);
      float g0 = xin[(size_t)(unsigned)a.x * 176 + f];
      float g1 = xin[(size_t)(unsigned)a.z * 176 + f];
      acc = fmaf(__int_as_float(a.y), g0, acc);
      acc = fmaf(__int_as_float(a.w), g1, acc);
    }
    if (e < end) {
      int2 q = cv[e];
      acc = fmaf(__int_as_float(q.y), xin[(size_t)(unsigned)q.x * 176 + f], acc);
    }
    if (lane < DIN) {
      float a = xv + acc, m = xv * acc;
      amp[(size_t)row * 64 + lane] = (unsigned)f2bf(a) | ((unsigned)f2bf(m) << 16);
    }
  }
}

// ---------------------------------------------------------------------------
// k_xf: MFMA transform (proven r13). Block = 64 rows, 4 waves.
//   xn = leaky(A@W1 + b1) + leaky(M@W2 + b2)
// A/M and transposed W1/W2 staged in XOR-swizzled LDS.
// Writes f32 out (+ bf16 gather table xh for the next layer, if non-null).
// ---------------------------------------------------------------------------
template <int DIN, int DOUT>
__global__ void __launch_bounds__(256) k_xf(
    const unsigned* __restrict__ amp,
    const float* __restrict__ W1, const float* __restrict__ b1,
    const float* __restrict__ W2, const float* __restrict__ b2,
    float* __restrict__ outp, unsigned short* __restrict__ xh, int n) {
  constexpr int ROWB = DIN * 2;          // LDS row stride (bytes)
  constexpr int RMASK = (ROWB / 16) - 1; // swizzle mask
  constexpr int NTC = DOUT / 16;
  __shared__ unsigned short sA[64 * DIN];
  __shared__ unsigned short sM[64 * DIN];
  __shared__ unsigned short sW1[DOUT * DIN];
  __shared__ unsigned short sW2[DOUT * DIN];

  int row0 = blockIdx.x * 64;

  constexpr int PAIRS = DIN / 2;
  for (int i = threadIdx.x; i < 64 * PAIRS; i += 256) {
    int r = i / PAIRS, fp = (i - r * PAIRS) * 2;
    unsigned lo = 0, hi = 0;
    if (row0 + r < n) {
      uint2 q = *(const uint2*)(amp + (size_t)(row0 + r) * 64 + fp);
      lo = (q.x & 0xffffu) | ((q.y & 0xffffu) << 16);  // a pair
      hi = (q.x >> 16) | (q.y & 0xffff0000u);          // m pair
    }
    int boffb = r * ROWB + ((fp * 2) ^ ((r & RMASK) << 4));
    *(unsigned*)((char*)sA + boffb) = lo;
    *(unsigned*)((char*)sM + boffb) = hi;
  }
  for (int i = threadIdx.x; i < DIN * DOUT; i += 256) {
    int k = i / DOUT, c = i - k * DOUT;
    int boffb = c * ROWB + ((k * 2) ^ ((c & RMASK) << 4));
    *(unsigned short*)((char*)sW1 + boffb) = f2bf(W1[i]);
    *(unsigned short*)((char*)sW2 + boffb) = f2bf(W2[i]);
  }
  __syncthreads();

  int w = threadIdx.x >> 6, l = threadIdx.x & 63;
  int tr = w;

  f4 acc1[NTC], acc2[NTC];
#pragma unroll
  for (int tc = 0; tc < NTC; ++tc) {
    acc1[tc] = (f4){0.0f, 0.0f, 0.0f, 0.0f};
    acc2[tc] = (f4){0.0f, 0.0f, 0.0f, 0.0f};
  }

#pragma unroll
  for (int k0 = 0; k0 < DIN; k0 += 32) {
    int ra = tr * 16 + (l & 15);
    int inb = (k0 + (l >> 4) * 8) * 2;
    s8v af = *(const s8v*)((const char*)sA + ra * ROWB + (inb ^ ((ra & RMASK) << 4)));
    s8v mf = *(const s8v*)((const char*)sM + ra * ROWB + (inb ^ ((ra & RMASK) << 4)));
#pragma unroll
    for (int tc = 0; tc < NTC; ++tc) {
      int rc = tc * 16 + (l & 15);
      int wb = rc * ROWB + (inb ^ ((rc & RMASK) << 4));
      s8v w1 = *(const s8v*)((const char*)sW1 + wb);
      s8v w2 = *(const s8v*)((const char*)sW2 + wb);
      acc1[tc] = __builtin_amdgcn_mfma_f32_16x16x32_bf16(af, w1, acc1[tc], 0, 0, 0);
      acc2[tc] = __builtin_amdgcn_mfma_f32_16x16x32_bf16(mf, w2, acc2[tc], 0, 0, 0);
    }
  }

#pragma unroll
  for (int tc = 0; tc < NTC; ++tc) {
    int c = tc * 16 + (l & 15);
    float bb1 = b1[c], bb2 = b2[c];
#pragma unroll
    for (int j = 0; j < 4; ++j) {
      int r = tr * 16 + (l >> 4) * 4 + j;
      if (row0 + r < n) {
        float v1 = acc1[tc][j] + bb1;
        float v2 = acc2[tc][j] + bb2;
        float xn = LEAKY(v1) + LEAKY(v2);
        outp[(size_t)(row0 + r) * 176 + c] = xn;
        if (xh) xh[(size_t)(row0 + r) * 64 + c] = f2bf(xn);
      }
    }
  }
}

// ---------------------------------------------------------------------------
// k_norm: L2-normalize cols [64,128), [128,160), [160,176) in place.
// ---------------------------------------------------------------------------
__global__ void __launch_bounds__(256) k_norm(float* out, int n) {
  int row = (int)((blockIdx.x * (unsigned)blockDim.x + threadIdx.x) >> 6);
  int lane = threadIdx.x & 63;
  if (row >= n) return;
  float* r = out + (size_t)row * 176;
  float a = r[64 + lane];
  float b = (lane < 48) ? r[128 + lane] : 0.0f;
  float sa = a * a;
  float sb_ = (lane < 32) ? b * b : 0.0f;
  float sc = (lane >= 32 && lane < 48) ? b * b : 0.0f;
#pragma unroll
  for (int off = 32; off; off >>= 1) {
    sa += __shfl_xor(sa, off);
    sb_ += __shfl_xor(sb_, off);
    sc += __shfl_xor(sc, off);
  }
  float ia = 1.0f / fmaxf(sqrtf(sa), 1e-12f);
  float ib = 1.0f / fmaxf(sqrtf(sb_), 1e-12f);
  float ic = 1.0f / fmaxf(sqrtf(sc), 1e-12f);
  r[64 + lane] = a * ia;
  if (lane < 48) r[128 + lane] = b * ((lane < 32) ? ib : ic);
}

// ---------------------------------------------------------------------------
extern "C" void kernel_launch(void* const* d_in, const int* in_sizes, int n_in,
                              void* d_out, int out_size, void* d_ws, size_t ws_size,
                              hipStream_t stream) {
  const float* ego = (const float*)d_in[0];
  const int* erow = (const int*)d_in[1];
  const int* ecol = (const int*)d_in[2];
  const float* ev = (const float*)d_in[3];
  const int n = in_sizes[0] / 64;  // 160000
  const int E = in_sizes[1];       // 5120000
  const int nb = (n + RPB - 1) >> SH;  // 313

  float* out = (float*)d_out;  // [n, 176] f32

  // ws: bkt[E] (amp overlays) | cv[E] | rp[n+1] | meta | xh[n*64] bf16
  // total ~103.1 MB (proven in rounds 11-13, 16, 17)
  int2* bkt = (int2*)d_ws;
  int2* cv = bkt + E;
  int* rp = (int*)(cv + E);
  int* bcnt = rp + n + 1;
  int* boff = bcnt + NBMAX;
  int* bcur = boff + NBMAX + 1;
  unsigned short* xh = (unsigned short*)(bcur + NBMAX);
  unsigned* amp = (unsigned*)d_ws;  // overlays bkt (dead after k_bsort)

  size_t need_bf = (size_t)((char*)(xh + (size_t)n * 64) - (char*)d_ws);
  bool bf = ws_size >= need_bf;

  const int rblocks = (n + 3) / 4;   // one wave per row
  const int xblocks = (n + 63) / 64; // 64 rows per block

  k_init<<<2048, 256, 0, stream>>>(ego, out, bf ? xh : (unsigned short*)d_ws, n);
  hipMemsetAsync(bcnt, 0, NBMAX * sizeof(int), stream);
  k_hist<<<1024, 256, 0, stream>>>(erow, bcnt, E, nb);
  k_scanb<<<1, 64, 0, stream>>>(bcnt, boff, bcur, rp, nb, n, E);
  k_bucket<<<(E + CHUNK - 1) / CHUNK, 256, 0, stream>>>(erow, ecol, ev, bcur, bkt, E, nb);
  k_bsort<<<nb, 512, 0, stream>>>(boff, bkt, cv, rp, n);
  // bkt dead from here; amp takes its space

  const float* W1_0 = (const float*)d_in[4];
  const float* B1_0 = (const float*)d_in[5];
  const float* W2_0 = (const float*)d_in[6];
  const float* B2_0 = (const float*)d_in[7];
  const float* W1_1 = (const float*)d_in[8];
  const float* B1_1 = (const float*)d_in[9];
  const float* W2_1 = (const float*)d_in[10];
  const float* B2_1 = (const float*)d_in[11];
  const float* W1_2 = (const float*)d_in[12];
  const float* B1_2 = (const float*)d_in[13];
  const float* W2_2 = (const float*)d_in[14];
  const float* B2_2 = (const float*)d_in[15];

  if (bf) {
    k_gam<64, true><<<rblocks, 256, 0, stream>>>(rp, cv, xh, out, amp, n);
    k_xf<64, 64><<<xblocks, 256, 0, stream>>>(amp, W1_0, B1_0, W2_0, B2_0, out + 64, xh, n);
    k_gam<64, true><<<rblocks, 256, 0, stream>>>(rp, cv, xh, out + 64, amp, n);
    k_xf<64, 32><<<xblocks, 256, 0, stream>>>(amp, W1_1, B1_1, W2_1, B2_1, out + 128, xh, n);
    k_gam<32, true><<<rblocks, 256, 0, stream>>>(rp, cv, xh, out + 128, amp, n);
    k_xf<32, 16><<<xblocks, 256, 0, stream>>>(amp, W1_2, B1_2, W2_2, B2_2, out + 160, nullptr, n);
  } else {
    k_gam<64, false><<<rblocks, 256, 0, stream>>>(rp, cv, nullptr, out, amp, n);
    k_xf<64, 64><<<xblocks, 256, 0, stream>>>(amp, W1_0, B1_0, W2_0, B2_0, out + 64, nullptr, n);
    k_gam<64, false><<<rblocks, 256, 0, stream>>>(rp, cv, nullptr, out + 64, amp, n);
    k_xf<64, 32><<<xblocks, 256, 0, stream>>>(amp, W1_1, B1_1, W2_1, B2_1, out + 128, nullptr, n);
    k_gam<32, false><<<rblocks, 256, 0, stream>>>(rp, cv, nullptr, out + 128, amp, n);
    k_xf<32, 16><<<xblocks, 256, 0, stream>>>(amp, W1_2, B1_2, W2_2, B2_2, out + 160, nullptr, n);
  }

  k_norm<<<rblocks, 256, 0, stream>>>(out, n);
}